// Round 1
// baseline (32.202 us; speedup 1.0000x reference)
//
#include <hip/hip_runtime.h>

#define NPOS 1024
#define BLK 256
#define NBATCH 64
#define DROW 2050

__global__ __launch_bounds__(256) void energy_kernel(const float* __restrict__ conf,
                                                     float* __restrict__ out) {
  __shared__ float px[NPOS], py[NPOS], pz[NPOS];
  __shared__ float tsx[BLK], tsy[BLK], tsz[BLK];
  __shared__ float red[4];

  const int tp = blockIdx.x % 10;   // upper-triangular tile-pair 0..9
  const int b  = blockIdx.x / 10;   // batch
  int ti, tj;
  if      (tp < 4) { ti = 0; tj = tp;     }
  else if (tp < 7) { ti = 1; tj = tp - 3; }
  else if (tp < 9) { ti = 2; tj = tp - 5; }
  else             { ti = 3; tj = 3;      }

  const int tid = threadIdx.x;
  const float* __restrict__ row = conf + b * DROW;

  // ---- phase 1: chain positions via block scan (4 steps per thread) ----
  // S[0] = 0, S[n] = step[n-1]; pos[n] = init + inclusive_scan(S)[n]
  float lx[4], ly[4], lz[4];
  float runx = 0.f, runy = 0.f, runz = 0.f;
  #pragma unroll
  for (int k = 0; k < 4; ++k) {
    const int n = 4 * tid + k;
    float sx = 0.f, sy = 0.f, sz = 0.f;
    if (n > 0) {
      const int m = n - 1;
      const float r1 = row[4 + 2 * m] + 0.5f;
      const float r2 = row[5 + 2 * m] + 0.5f;
      const float ct = 1.f - 2.f * r2;                    // cos(theta)
      const float st = sqrtf(fmaxf(0.f, 1.f - ct * ct));  // sin(theta) >= 0 on [0,pi]
      const float sp = __builtin_amdgcn_sinf(r1);         // sin(2*pi*r1): hw takes revolutions
      const float cp = __builtin_amdgcn_cosf(r1);         // cos(2*pi*r1)
      sx = st * cp; sy = st * sp; sz = ct;
    }
    runx += sx; runy += sy; runz += sz;
    lx[k] = runx; ly[k] = runy; lz[k] = runz;
  }
  tsx[tid] = runx; tsy[tid] = runy; tsz[tid] = runz;
  __syncthreads();
  // Hillis-Steele inclusive scan over 256 thread totals
  for (int off = 1; off < BLK; off <<= 1) {
    float ax = 0.f, ay = 0.f, az = 0.f;
    if (tid >= off) { ax = tsx[tid - off]; ay = tsy[tid - off]; az = tsz[tid - off]; }
    __syncthreads();
    if (tid >= off) { tsx[tid] += ax; tsy[tid] += ay; tsz[tid] += az; }
    __syncthreads();
  }
  const float ox = (tid > 0) ? tsx[tid - 1] : 0.f;
  const float oy = (tid > 0) ? tsy[tid - 1] : 0.f;
  const float oz = (tid > 0) ? tsz[tid - 1] : 0.f;
  const float ix = row[1], iy = row[2], iz = row[3];
  #pragma unroll
  for (int k = 0; k < 4; ++k) {
    const int n = 4 * tid + k;
    px[n] = ix + ox + lx[k];
    py[n] = iy + oy + ly[k];
    pz[n] = iz + oz + lz[k];
  }
  __syncthreads();

  // ---- phase 2: pair energies for tile (ti, tj), i < j only ----
  const int i = ti * BLK + tid;
  const float xi = px[i], yi = py[i], zi = pz[i];
  const int jbase = tj * BLK;
  const float K = -5.770780163555856f;  // -4 * log2(e):  exp(-4*d2) = exp2(K*d2)
  float acc = 0.f;

  if (ti == tj) {
    #pragma unroll 4
    for (int jj = 0; jj < BLK; ++jj) {
      const int j = jbase + jj;
      const float dx = xi - px[j];
      const float dy = yi - py[j];
      const float dz = zi - pz[j];
      const float d2 = dx * dx + dy * dy + dz * dz;
      const float e = __builtin_amdgcn_exp2f(d2 * K);
      acc += ((j > i) && (d2 > 0.f)) ? e : 0.f;
    }
  } else {
    #pragma unroll 4
    for (int jj = 0; jj < BLK; ++jj) {
      const int j = jbase + jj;
      const float dx = xi - px[j];
      const float dy = yi - py[j];
      const float dz = zi - pz[j];
      const float d2 = dx * dx + dy * dy + dz * dz;
      const float e = __builtin_amdgcn_exp2f(d2 * K);
      acc += (d2 > 0.f) ? e : 0.f;
    }
  }

  // ---- reduce: wave shuffle -> LDS -> one atomic per block ----
  #pragma unroll
  for (int off2 = 32; off2 > 0; off2 >>= 1) acc += __shfl_down(acc, off2, 64);
  const int lane = tid & 63, wave = tid >> 6;
  if (lane == 0) red[wave] = acc;
  __syncthreads();
  if (tid == 0) {
    // x2 for (i,j)/(j,i) symmetry, x SIGMA=10
    atomicAdd(out, 20.0f * (red[0] + red[1] + red[2] + red[3]));
  }
}

extern "C" void kernel_launch(void* const* d_in, const int* in_sizes, int n_in,
                              void* d_out, int out_size, void* d_ws, size_t ws_size,
                              hipStream_t stream) {
  const float* conf = (const float*)d_in[0];
  float* out = (float*)d_out;
  hipMemsetAsync(out, 0, sizeof(float) * out_size, stream);
  hipLaunchKernelGGL(energy_kernel, dim3(NBATCH * 10), dim3(BLK), 0, stream, conf, out);
}

// Round 2
// 26.592 us; speedup vs baseline: 1.2110x; 1.2110x over previous
//
#include <hip/hip_runtime.h>

#define NPOS 1024
#define NBATCH 64
#define DROW 2050
#define T 8          // i/j tiles per batch
#define TS 128       // tile size
#define NTP 36       // T*(T+1)/2 triangular tile pairs

// ---------------- kernel 1: chain positions, pre-scaled ----------------
// pos[n] = ALPHA * (init + cumsum(steps))   with ALPHA = sqrt(4*log2(e))
// so that exp(-4*d2) == exp2(-|dpos|^2) in the pair kernel.
__global__ __launch_bounds__(256) void pos_kernel(const float* __restrict__ conf,
                                                  float4* __restrict__ pos) {
  const int b = blockIdx.x;
  const int tid = threadIdx.x;
  const float* __restrict__ row = conf + b * DROW;
  const float ALPHA = 2.40224481f;  // sqrt(5.770780163555856)

  // local 4-step running sums
  float lx[4], ly[4], lz[4];
  float rx = 0.f, ry = 0.f, rz = 0.f;
  #pragma unroll
  for (int k = 0; k < 4; ++k) {
    const int n = 4 * tid + k;
    if (n > 0) {
      // r-pair for step m=n-1 lives at row[8*tid + 2*k + 2], 8B aligned
      const float2 rr = *reinterpret_cast<const float2*>(row + 8 * tid + 2 * k + 2);
      const float r1 = rr.x + 0.5f;
      const float r2 = rr.y + 0.5f;
      const float ct = 1.f - 2.f * r2;                    // cos(theta)
      const float st = sqrtf(fmaxf(0.f, 1.f - ct * ct));  // sin(theta)
      const float sp = __builtin_amdgcn_sinf(r1);         // sin(2*pi*r1), hw rev input
      const float cp = __builtin_amdgcn_cosf(r1);
      rx += st * cp; ry += st * sp; rz += ct;
    }
    lx[k] = rx; ly[k] = ry; lz[k] = rz;
  }

  // inclusive wave scan of thread totals via shfl_up (no barriers)
  const int lane = tid & 63, w = tid >> 6;
  const float tx = rx, ty = ry, tz = rz;
  float sx = rx, sy = ry, sz = rz;
  #pragma unroll
  for (int off = 1; off < 64; off <<= 1) {
    const float ax = __shfl_up(sx, off, 64);
    const float ay = __shfl_up(sy, off, 64);
    const float az = __shfl_up(sz, off, 64);
    if (lane >= off) { sx += ax; sy += ay; sz += az; }
  }
  // cross-wave prefix
  __shared__ float wx[4], wy[4], wz[4];
  if (lane == 63) { wx[w] = sx; wy[w] = sy; wz[w] = sz; }
  __syncthreads();
  float cx = 0.f, cy = 0.f, cz = 0.f;
  #pragma unroll
  for (int ww = 0; ww < 3; ++ww) {
    if (ww < w) { cx += wx[ww]; cy += wy[ww]; cz += wz[ww]; }
  }

  const float ox = row[1] + cx + (sx - tx);  // init + exclusive prefix
  const float oy = row[2] + cy + (sy - ty);
  const float oz = row[3] + cz + (sz - tz);
  float4* __restrict__ bp = pos + b * NPOS;
  #pragma unroll
  for (int k = 0; k < 4; ++k) {
    bp[4 * tid + k] = make_float4(ALPHA * (ox + lx[k]),
                                  ALPHA * (oy + ly[k]),
                                  ALPHA * (oz + lz[k]), 0.f);
  }
}

// ---------------- kernel 2: pair energies over triangular 128-tiles ----------------
__global__ __launch_bounds__(128) void pair_kernel(const float4* __restrict__ pos,
                                                   float* __restrict__ part) {
  const int bx = blockIdx.x;
  const int b = bx / NTP;
  int rem = bx % NTP;
  int ti = 0;
  while (rem >= T - ti) { rem -= T - ti; ++ti; }  // scalar, <=8 iters
  const int tj = ti + rem;

  const int tid = threadIdx.x;
  __shared__ float4 PJ[TS];
  const float4* __restrict__ bp = pos + b * NPOS;
  PJ[tid] = bp[tj * TS + tid];
  const float4 pi = bp[ti * TS + tid];
  __syncthreads();

  float a0 = 0.f, a1 = 0.f, a2 = 0.f, a3 = 0.f;
  if (ti != tj) {
    #pragma unroll 4
    for (int jj = 0; jj < TS; jj += 4) {
      const float4 q0 = PJ[jj + 0];
      const float4 q1 = PJ[jj + 1];
      const float4 q2 = PJ[jj + 2];
      const float4 q3 = PJ[jj + 3];
      float dx, dy, dz, d2;
      dx = pi.x - q0.x; dy = pi.y - q0.y; dz = pi.z - q0.z;
      d2 = dx * dx + dy * dy + dz * dz; a0 += __builtin_amdgcn_exp2f(-d2);
      dx = pi.x - q1.x; dy = pi.y - q1.y; dz = pi.z - q1.z;
      d2 = dx * dx + dy * dy + dz * dz; a1 += __builtin_amdgcn_exp2f(-d2);
      dx = pi.x - q2.x; dy = pi.y - q2.y; dz = pi.z - q2.z;
      d2 = dx * dx + dy * dy + dz * dz; a2 += __builtin_amdgcn_exp2f(-d2);
      dx = pi.x - q3.x; dy = pi.y - q3.y; dz = pi.z - q3.z;
      d2 = dx * dx + dy * dy + dz * dz; a3 += __builtin_amdgcn_exp2f(-d2);
    }
  } else {
    #pragma unroll 4
    for (int jj = 0; jj < TS; jj += 4) {
      const float4 q0 = PJ[jj + 0];
      const float4 q1 = PJ[jj + 1];
      const float4 q2 = PJ[jj + 2];
      const float4 q3 = PJ[jj + 3];
      float dx, dy, dz, d2;
      dx = pi.x - q0.x; dy = pi.y - q0.y; dz = pi.z - q0.z;
      d2 = dx * dx + dy * dy + dz * dz;
      a0 += (jj + 0 > tid) ? __builtin_amdgcn_exp2f(-d2) : 0.f;
      dx = pi.x - q1.x; dy = pi.y - q1.y; dz = pi.z - q1.z;
      d2 = dx * dx + dy * dy + dz * dz;
      a1 += (jj + 1 > tid) ? __builtin_amdgcn_exp2f(-d2) : 0.f;
      dx = pi.x - q2.x; dy = pi.y - q2.y; dz = pi.z - q2.z;
      d2 = dx * dx + dy * dy + dz * dz;
      a2 += (jj + 2 > tid) ? __builtin_amdgcn_exp2f(-d2) : 0.f;
      dx = pi.x - q3.x; dy = pi.y - q3.y; dz = pi.z - q3.z;
      d2 = dx * dx + dy * dy + dz * dz;
      a3 += (jj + 3 > tid) ? __builtin_amdgcn_exp2f(-d2) : 0.f;
    }
  }

  float acc = (a0 + a1) + (a2 + a3);
  #pragma unroll
  for (int off = 32; off; off >>= 1) acc += __shfl_down(acc, off, 64);
  __shared__ float red[2];
  if ((tid & 63) == 0) red[tid >> 6] = acc;
  __syncthreads();
  if (tid == 0) part[bx] = red[0] + red[1];
}

// ---------------- kernel 3: final reduce ----------------
__global__ __launch_bounds__(256) void reduce_kernel(const float* __restrict__ part,
                                                     float* __restrict__ out, int n) {
  float s = 0.f;
  for (int i = threadIdx.x; i < n; i += 256) s += part[i];
  #pragma unroll
  for (int off = 32; off; off >>= 1) s += __shfl_down(s, off, 64);
  __shared__ float red[4];
  const int lane = threadIdx.x & 63, w = threadIdx.x >> 6;
  if (lane == 0) red[w] = s;
  __syncthreads();
  if (threadIdx.x == 0) out[0] = 20.0f * (red[0] + red[1] + red[2] + red[3]);  // 2*SIGMA
}

extern "C" void kernel_launch(void* const* d_in, const int* in_sizes, int n_in,
                              void* d_out, int out_size, void* d_ws, size_t ws_size,
                              hipStream_t stream) {
  const float* conf = (const float*)d_in[0];
  float* out = (float*)d_out;
  float4* pos = (float4*)d_ws;                                   // 64*1024*16B = 1 MB
  float* part = (float*)((char*)d_ws + NBATCH * NPOS * sizeof(float4));  // 2304 floats

  hipLaunchKernelGGL(pos_kernel, dim3(NBATCH), dim3(256), 0, stream, conf, pos);
  hipLaunchKernelGGL(pair_kernel, dim3(NBATCH * NTP), dim3(TS), 0, stream, pos, part);
  hipLaunchKernelGGL(reduce_kernel, dim3(1), dim3(256), 0, stream, part, out,
                     NBATCH * NTP);
}